// Round 1
// baseline (217.914 us; speedup 1.0000x reference)
//
#include <hip/hip_runtime.h>

// AffineTransform2D: im [MB=8, D=32, H=256, W=256, C=4] f32, thetas [8,6] f32
// out [8, 32, 256, 256, 4] f32.
// One thread per (b, r, s) spatial output pixel; loops over D.
// block = 256 threads = one output row (b, r block-uniform -> scalar theta loads).

#define MB_ 8
#define D_  32
#define H_  256
#define W_  256
#define C_  4

__global__ __launch_bounds__(256) void affine2d_kernel(
    const float* __restrict__ im,
    const float* __restrict__ thetas,
    float* __restrict__ out)
{
    const int s = threadIdx.x;             // W index (fastest, coalesced)
    const int r = blockIdx.x & (H_ - 1);   // H index (block-uniform)
    const int b = blockIdx.x >> 8;         // batch  (block-uniform)

    // thetas are block-uniform -> scalar loads via SGPR
    const float t0 = thetas[b * 6 + 0];
    const float t1 = thetas[b * 6 + 1];
    const float t2 = thetas[b * 6 + 2];
    const float t3 = thetas[b * 6 + 3];
    const float t4 = thetas[b * 6 + 4];
    const float t5 = thetas[b * 6 + 5];

    // flat_coords for output pixel (r,s):  x_in = linspace(-1,1,H)[s],
    // y_in = linspace(-1,1,W)[r]   (H==W==256 so both step 2/255)
    const float x_in = -1.0f + (float)s * (2.0f / 255.0f);
    const float y_in = -1.0f + (float)r * (2.0f / 255.0f);

    const float Xc = (t0 * x_in + t1 * y_in + t2 + 1.0f) * 0.5f * (float)W_;
    const float Yc = (t3 * x_in + t4 * y_in + t5 + 1.0f) * 0.5f * (float)H_;

    int x0i = (int)floorf(Xc);
    int y0i = (int)floorf(Yc);
    int x1i = x0i + 1;
    int y1i = y0i + 1;
    x0i = min(max(x0i, 0), W_ - 1);
    x1i = min(max(x1i, 0), W_ - 1);
    y0i = min(max(y0i, 0), H_ - 1);
    y1i = min(max(y1i, 0), H_ - 1);

    // weights from CLIPPED corner coords (matches reference exactly)
    const float x0f = (float)x0i, x1f = (float)x1i;
    const float y0f = (float)y0i, y1f = (float)y1i;
    const float wa = (x1f - Xc) * (y1f - Yc);
    const float wb = (x1f - Xc) * (Yc - y0f);
    const float wc = (Xc - x0f) * (y1f - Yc);
    const float wd = (Xc - x0f) * (Yc - y0f);

    const float4* __restrict__ imv  = (const float4*)im;   // C=4 contiguous
    float4*       __restrict__ outv = (float4*)out;

    const int plane = H_ * W_;                 // float4s per (b,d) plane
    const int ia = y0i * W_ + x0i;
    const int ib = y1i * W_ + x0i;
    const int ic = y0i * W_ + x1i;
    const int id = y1i * W_ + x1i;

    int inBase = b * D_ * plane;
    int outIdx = b * D_ * plane + r * W_ + s;

#pragma unroll 4
    for (int d = 0; d < D_; ++d) {
        const float4 va = imv[inBase + ia];
        const float4 vb = imv[inBase + ib];
        const float4 vc = imv[inBase + ic];
        const float4 vd = imv[inBase + id];
        float4 o;
        o.x = va.x * wa + vb.x * wb + vc.x * wc + vd.x * wd;
        o.y = va.y * wa + vb.y * wb + vc.y * wc + vd.y * wd;
        o.z = va.z * wa + vb.z * wb + vc.z * wc + vd.z * wd;
        o.w = va.w * wa + vb.w * wb + vc.w * wc + vd.w * wd;
        outv[outIdx] = o;
        inBase += plane;
        outIdx += plane;
    }
}

extern "C" void kernel_launch(void* const* d_in, const int* in_sizes, int n_in,
                              void* d_out, int out_size, void* d_ws, size_t ws_size,
                              hipStream_t stream) {
    const float* im     = (const float*)d_in[0];
    const float* thetas = (const float*)d_in[1];
    float* out          = (float*)d_out;

    dim3 grid(MB_ * H_);   // 2048 blocks, one per (b, r) row
    dim3 block(W_);        // 256 threads, one per s
    affine2d_kernel<<<grid, block, 0, stream>>>(im, thetas, out);
}

// Round 2
// 119.293 us; speedup vs baseline: 1.8267x; 1.8267x over previous
//
#include <hip/hip_runtime.h>

// AffineTransform2D via LDS-staged bilinear sampling.
// im [8,32,256,256,4] f32, thetas [8,6] f32 -> out [8,32,256,256,4] f32.
// Block = 16x16 output tile for one (b). Affine bbox of the tile's source
// region is <= ~33x33 float4 (thetas in [0,1)), staged per d-plane into LDS
// with coalesced loads; the 4 bilinear taps gather from LDS instead of L1
// (kills the gather/TA serialization seen in round 0).

#define MB_ 8
#define D_  32
#define H_  256
#define W_  256

#define TS 16           // tile width  (s)
#define TR 16           // tile height (r)
#define CAP 34          // max staged region dim (float4s)
#define CAPE ((CAP*CAP + 255) / 256)   // staging elems per thread (5)

__global__ __launch_bounds__(256) void affine2d_tiled(
    const float* __restrict__ im,
    const float* __restrict__ thetas,
    float* __restrict__ out)
{
    __shared__ float4 tile[CAP * CAP];   // 18,496 B
    __shared__ int red[16];              // per-wave bbox scratch

    const int tid = threadIdx.x;
    const int sl  = tid & (TS - 1);
    const int rl  = tid >> 4;
    const int bIdx = blockIdx.x;
    const int s0 = (bIdx & 15) * TS;
    const int r0 = ((bIdx >> 4) & 15) * TR;
    const int b  = bIdx >> 8;

    const float t0 = thetas[b*6+0], t1 = thetas[b*6+1], t2 = thetas[b*6+2];
    const float t3 = thetas[b*6+3], t4 = thetas[b*6+4], t5 = thetas[b*6+5];

    const int s = s0 + sl, r = r0 + rl;
    const float x_in = -1.0f + (float)s * (2.0f / 255.0f);
    const float y_in = -1.0f + (float)r * (2.0f / 255.0f);
    const float Xc = (t0*x_in + t1*y_in + t2 + 1.0f) * 0.5f * (float)W_;
    const float Yc = (t3*x_in + t4*y_in + t5 + 1.0f) * 0.5f * (float)H_;

    int x0i = (int)floorf(Xc), y0i = (int)floorf(Yc);
    int x1i = x0i + 1,         y1i = y0i + 1;
    x0i = min(max(x0i, 0), W_-1);  x1i = min(max(x1i, 0), W_-1);
    y0i = min(max(y0i, 0), H_-1);  y1i = min(max(y1i, 0), H_-1);

    // weights from CLIPPED corners (matches reference bit pattern)
    const float wa = ((float)x1i - Xc) * ((float)y1i - Yc);
    const float wb = ((float)x1i - Xc) * (Yc - (float)y0i);
    const float wc = (Xc - (float)x0i) * ((float)y1i - Yc);
    const float wd = (Xc - (float)x0i) * (Yc - (float)y0i);

    // ---- exact block bounding box via reduction (robust for any thetas) ----
    int xmn = x0i, xmx = x1i, ymn = y0i, ymx = y1i;
#pragma unroll
    for (int off = 32; off; off >>= 1) {
        xmn = min(xmn, __shfl_xor(xmn, off));
        xmx = max(xmx, __shfl_xor(xmx, off));
        ymn = min(ymn, __shfl_xor(ymn, off));
        ymx = max(ymx, __shfl_xor(ymx, off));
    }
    const int wv = tid >> 6;
    if ((tid & 63) == 0) {
        red[wv*4+0] = xmn; red[wv*4+1] = xmx;
        red[wv*4+2] = ymn; red[wv*4+3] = ymx;
    }
    __syncthreads();
    const int xlo = min(min(red[0], red[4]),  min(red[8],  red[12]));
    const int xhi = max(max(red[1], red[5]),  max(red[9],  red[13]));
    const int ylo = min(min(red[2], red[6]),  min(red[10], red[14]));
    const int yhi = max(max(red[3], red[7]),  max(red[11], red[15]));
    const int nx = xhi - xlo + 1;
    const int ny = yhi - ylo + 1;

    const int plane = H_ * W_;
    const float4* __restrict__ imb = (const float4*)im + b * (D_ * plane);
    float4* __restrict__ outp = (float4*)out + b * (D_ * plane) + r * W_ + s;

    if (nx <= CAP && ny <= CAP) {
        // ---------------- LDS-staged path (always taken for this input) ----
        const int total = nx * ny;
        int goff[CAPE];
        int ne = 0;
        for (int e = tid; e < total; e += 256) {
            const int yy = e / nx;
            const int xx = e - yy * nx;
            goff[ne++] = (ylo + yy) * W_ + (xlo + xx);
        }
        const int la = (y0i - ylo) * nx + (x0i - xlo);
        const int lb = (y1i - ylo) * nx + (x0i - xlo);
        const int dx = x1i - x0i;

        float4 pre[CAPE];
        for (int k = 0; k < ne; ++k) pre[k] = imb[goff[k]];   // d = 0

        for (int d = 0; d < D_; ++d) {
            __syncthreads();                       // prev compute done
            for (int k = 0; k < ne; ++k) tile[tid + (k << 8)] = pre[k];
            __syncthreads();
            if (d + 1 < D_) {                      // prefetch next plane
                const float4* pl = imb + (d + 1) * plane;
                for (int k = 0; k < ne; ++k) pre[k] = pl[goff[k]];
            }
            const float4 va = tile[la];
            const float4 vb = tile[lb];
            const float4 vc = tile[la + dx];
            const float4 vd = tile[lb + dx];
            float4 o;
            o.x = va.x*wa + vb.x*wb + vc.x*wc + vd.x*wd;
            o.y = va.y*wa + vb.y*wb + vc.y*wc + vd.y*wd;
            o.z = va.z*wa + vb.z*wb + vc.z*wc + vd.z*wd;
            o.w = va.w*wa + vb.w*wb + vc.w*wc + vd.w*wd;
            outp[d * plane] = o;
        }
    } else {
        // ---------------- fallback: direct global gathers ------------------
        const int ia = y0i * W_ + x0i;
        const int ib = y1i * W_ + x0i;
        const int ic = y0i * W_ + x1i;
        const int id = y1i * W_ + x1i;
        for (int d = 0; d < D_; ++d) {
            const float4* pl = imb + d * plane;
            const float4 va = pl[ia], vb = pl[ib], vc = pl[ic], vd = pl[id];
            float4 o;
            o.x = va.x*wa + vb.x*wb + vc.x*wc + vd.x*wd;
            o.y = va.y*wa + vb.y*wb + vc.y*wc + vd.y*wd;
            o.z = va.z*wa + vb.z*wb + vc.z*wc + vd.z*wd;
            o.w = va.w*wa + vb.w*wb + vc.w*wc + vd.w*wd;
            outp[d * plane] = o;
        }
    }
}

extern "C" void kernel_launch(void* const* d_in, const int* in_sizes, int n_in,
                              void* d_out, int out_size, void* d_ws, size_t ws_size,
                              hipStream_t stream) {
    const float* im     = (const float*)d_in[0];
    const float* thetas = (const float*)d_in[1];
    float* out          = (float*)d_out;

    dim3 grid(MB_ * (H_ / TR) * (W_ / TS));   // 8 * 16 * 16 = 2048
    dim3 block(TS * TR);                      // 256
    affine2d_tiled<<<grid, block, 0, stream>>>(im, thetas, out);
}